// Round 2
// baseline (282.935 us; speedup 1.0000x reference)
//
#include <hip/hip_runtime.h>
#include <cstdint>
#include <cstddef>

// Problem constants (reference: B=4, T=4096, E=1024, M=E/2=512)
#define Tdim 4096
#define Bdim 4
#define Edim 1024
#define Mdim 512
#define EPSF 1e-6f

typedef __bf16 bf16x8 __attribute__((ext_vector_type(8)));
typedef float f32x4 __attribute__((ext_vector_type(4)));

// float -> bf16 bits, round-to-nearest-even
__device__ __forceinline__ unsigned short f2bf(float f) {
  union { float f; unsigned int u; } a; a.f = f;
  unsigned int r = a.u + 0x7fffu + ((a.u >> 16) & 1u);
  return (unsigned short)(r >> 16);
}

// bump kernel g(u) = exp(1 - 1/(1-u^2+eps)); reference's u>=1-EPS clamp can
// never fire for j<=T-1 (u_max = 1 - 1/horizon), so it is omitted.
__device__ __forceinline__ float kernel_g(float dj, float inv_h) {
  float u = fminf(dj * inv_h, 1.0f - EPSF);
  return __expf(1.0f - 1.0f / (1.0f - u * u + EPSF));
}

typedef void __attribute__((address_space(1)))* gas1;
typedef void __attribute__((address_space(3)))* las3;
// async global->LDS, 16B per lane; LDS dest = wave-uniform base + lane*16
__device__ __forceinline__ void load_lds16(const void* g, void* l) {
  __builtin_amdgcn_global_load_lds((gas1)(g), (las3)(l), 16, 0, 0);
}

// ---------------- prep kernels ----------------

__global__ __launch_bounds__(256) void gate_kernel(const float* __restrict__ graw,
                                                   float* __restrict__ gate) {
  const int m = blockIdx.x * 256 + threadIdx.x;
  if (m < Mdim) {
    const float v = graw[m];
    gate[m] = fmaxf(v, 0.0f) + log1pf(__expf(-fabsf(v)));  // stable softplus
  }
}

__global__ __launch_bounds__(256) void rowsum_kernel(float* __restrict__ inv_rowsum) {
  const int i = blockIdx.x;
  const int tid = threadIdx.x;
  const float inv_h = 1.0f / (float)(Tdim - i);
  float s = 0.0f;
  for (int j = i + tid; j < Tdim; j += 256)
    s += kernel_g((float)(j - i), inv_h);
#pragma unroll
  for (int off = 32; off; off >>= 1) s += __shfl_down(s, off);
  __shared__ float red[4];
  if ((tid & 63) == 0) red[tid >> 6] = s;
  __syncthreads();
  if (tid == 0) inv_rowsum[i] = 1.0f / (red[0] + red[1] + red[2] + red[3]);
}

// K matrix, normalized, bf16, zeros below diagonal. grid (2, T)
__global__ __launch_bounds__(256) void kgen_kernel(const float* __restrict__ inv_rowsum,
                                                   unsigned short* __restrict__ Kmat) {
  const int i = blockIdx.y;
  const int j0 = (blockIdx.x * 256 + threadIdx.x) * 8;
  union { unsigned short u[8]; uint4 v; } pk;
  if (j0 + 7 < i) {
    pk.v = make_uint4(0u, 0u, 0u, 0u);
  } else {
    const float inv_h = 1.0f / (float)(Tdim - i);
    const float inv_s = inv_rowsum[i];
#pragma unroll
    for (int t = 0; t < 8; ++t) {
      const int j = j0 + t;
      float r = 0.0f;
      if (j >= i) r = kernel_g((float)(j - i), inv_h) * inv_s;
      pk.u[t] = f2bf(r);
    }
  }
  *reinterpret_cast<uint4*>(&Kmat[(size_t)i * Tdim + j0]) = pk.v;
}

// XcT[b][m][j] = bf16(x[b][j][2m])  (transposed so GEMM B-frag is k-contiguous)
// tile: 64 j x 32 m per block. grid (T/64, M/32, B)
__global__ __launch_bounds__(256) void extract_kernel(const float* __restrict__ x,
                                                      unsigned short* __restrict__ XcT) {
  __shared__ unsigned short Ls[32][68];
  const int j0 = blockIdx.x * 64;
  const int m0 = blockIdx.y * 32;
  const int b  = blockIdx.z;
  const int tid = threadIdx.x;
  const int q = tid & 15;        // float4 chunk along e
  const int jbase = tid >> 4;    // 0..15
#pragma unroll
  for (int it = 0; it < 4; ++it) {
    const int jj = jbase + it * 16;
    const size_t off = ((size_t)(b * Tdim + j0 + jj)) * Edim + 2 * m0 + 4 * q;
    const float4 v = *reinterpret_cast<const float4*>(&x[off]);
    Ls[2 * q][jj]     = f2bf(v.x);   // even channel of m0+2q
    Ls[2 * q + 1][jj] = f2bf(v.z);   // even channel of m0+2q+1
  }
  __syncthreads();
  const int ch = tid & 15;
  const int mb = tid >> 4;
#pragma unroll
  for (int it = 0; it < 2; ++it) {
    const int m = mb + it * 16;
    ushort4 uv;
    uv.x = Ls[m][4 * ch];
    uv.y = Ls[m][4 * ch + 1];
    uv.z = Ls[m][4 * ch + 2];
    uv.w = Ls[m][4 * ch + 3];
    *reinterpret_cast<ushort4*>(
        &XcT[((size_t)(b * Mdim + m0 + m)) * Tdim + j0 + 4 * ch]) = uv;
  }
}

// ---------------- split-K GEMM: phi[b,i,m] += K[i, jstart:jend] @ Xc[b, jstart:jend, m] --------
// C-tile 128(i) x 128(m), BK=64, 4 waves, 4x4 frags of 16x16x32 per wave.
// blockIdx.x encodes (i-tile p, j-chunk q); chunks are uniform 16 iterations
// (last chunk of an i-tile may be shorter) -> 80 chunk-blocks per (m,b),
// grid 1280 blocks, ~5/CU: kills the triangular load imbalance.
// LDS uses XOR swizzle: 16B slot s of row r holds logical chunk s^(r&7)
// (applied by permuting the per-lane GLOBAL source address, since
// global_load_lds forces dest = base + lane*16). Fragment reads then hit
// all 32 banks (2-way aliasing only, which is free).
__global__ __launch_bounds__(256) void gemm_kernel(
    const unsigned short* __restrict__ Kmat,
    const unsigned short* __restrict__ XcT,
    float* __restrict__ phi) {
  // decode blockIdx.x -> (p, q):  nchunks(p) = ceil((64-2p)/16)
  int bx = blockIdx.x;
  int p = 0;
  int nc = 4;
  while (bx >= nc) { bx -= nc; ++p; nc = (64 - 2 * p + 15) >> 4; }
  const int q = bx;
  const int i0 = p * 128;
  const int m0 = blockIdx.y * 128;
  const int b  = blockIdx.z;
  const int jstart = i0 + q * 1024;
  const int jend   = min(jstart + 1024, Tdim);

  __shared__ unsigned short As[128 * 64];  // K rows i0.., swizzled 16B slots
  __shared__ unsigned short Bs[128 * 64];  // XcT rows m0.., swizzled
  const int tid = threadIdx.x;
  const int w = tid >> 6;
  const int l = tid & 63;
  f32x4 acc[4][4] = {};
  const int wr = w >> 1, wc = w & 1;
  const unsigned short* Arow = Kmat + (size_t)i0 * Tdim;
  const unsigned short* Brow = XcT + ((size_t)b * Mdim + m0) * Tdim;
  const int srow  = l >> 3;                   // row within 8-row group
  const int sslot = l & 7;                    // linear 16B slot this lane fills
  const int schunk = (sslot ^ srow) * 8;      // swizzled source chunk (bf16 units)

  for (int j0 = jstart; j0 < jend; j0 += 64) {
#pragma unroll
    for (int t = 0; t < 4; ++t) {
      const int rr = (w * 4 + t) * 8 + srow;
      load_lds16(Arow + (size_t)rr * Tdim + (j0 + schunk), &As[(w * 4 + t) * 512]);
      load_lds16(Brow + (size_t)rr * Tdim + (j0 + schunk), &Bs[(w * 4 + t) * 512]);
    }
    __syncthreads();  // drains vmcnt (global_load_lds) per gfx950 semantics
    const int lr16 = l & 15;
    const int kq = l >> 4;  // 0..3: which 16B chunk quarter of the k-dim
#pragma unroll
    for (int kk = 0; kk < 2; ++kk) {
      bf16x8 af[4], bfr[4];
      const int chunk = kk * 4 + kq;
      const int slot = (chunk ^ (lr16 & 7)) * 8;   // un-swizzle
#pragma unroll
      for (int r = 0; r < 4; ++r)
        af[r] = *reinterpret_cast<const bf16x8*>(&As[(wr * 64 + r * 16 + lr16) * 64 + slot]);
#pragma unroll
      for (int c = 0; c < 4; ++c)
        bfr[c] = *reinterpret_cast<const bf16x8*>(&Bs[(wc * 64 + c * 16 + lr16) * 64 + slot]);
#pragma unroll
      for (int r = 0; r < 4; ++r)
#pragma unroll
        for (int c = 0; c < 4; ++c)
          acc[r][c] = __builtin_amdgcn_mfma_f32_16x16x32_bf16(af[r], bfr[c], acc[r][c], 0, 0, 0);
    }
    __syncthreads();
  }

  // accumulate into phi (fp32, zero-initialized). C/D layout: col=lane&15 (m),
  // row=(lane>>4)*4+reg (i). Lanes 0-15 hit consecutive m -> coalesced atomics.
  const int lr = l & 15;
  const int lq = l >> 4;
#pragma unroll
  for (int r = 0; r < 4; ++r) {
    const int i = i0 + wr * 64 + r * 16 + lq * 4;
#pragma unroll
    for (int c = 0; c < 4; ++c) {
      const int m = m0 + wc * 64 + c * 16 + lr;
#pragma unroll
      for (int v = 0; v < 4; ++v)
        atomicAdd(&phi[((size_t)(b * Tdim + i + v)) * Mdim + m], acc[r][c][v]);
    }
  }
}

// ---------------- finalize: out even = x even (exact), odd = phi*gate ----------------
__global__ __launch_bounds__(256) void finalize_kernel(const float* __restrict__ x,
                                                       const float* __restrict__ phi,
                                                       const float* __restrict__ gate,
                                                       float* __restrict__ out) {
  const size_t idx = (size_t)blockIdx.x * 256 + threadIdx.x;  // float4 index
  const size_t o = idx * 4;
  const int e = (int)(o & (size_t)(Edim - 1));
  const size_t bt = o >> 10;  // / Edim
  const int m = e >> 1;
  const float4 xv = *reinterpret_cast<const float4*>(&x[o]);
  const float2 ph = *reinterpret_cast<const float2*>(&phi[bt * Mdim + m]);
  const float2 g  = *reinterpret_cast<const float2*>(&gate[m]);
  float4 r;
  r.x = xv.x;
  r.y = ph.x * g.x;
  r.z = xv.z;
  r.w = ph.y * g.y;
  *reinterpret_cast<float4*>(&out[o]) = r;
}

// ---------------- slow-but-correct fallback (only if ws too small) ----------------
__global__ __launch_bounds__(256) void fallback_kernel(const float* __restrict__ x,
                                                       const float* __restrict__ graw,
                                                       float* __restrict__ out) {
  const int i = blockIdx.x, b = blockIdx.y, tid = threadIdx.x;
  const float inv_h = 1.0f / (float)(Tdim - i);
  float s = 0.0f;
  for (int j = i + tid; j < Tdim; j += 256)
    s += kernel_g((float)(j - i), inv_h);
#pragma unroll
  for (int off = 32; off; off >>= 1) s += __shfl_down(s, off);
  __shared__ float red[4];
  __shared__ float sinv_sh;
  if ((tid & 63) == 0) red[tid >> 6] = s;
  __syncthreads();
  if (tid == 0) sinv_sh = 1.0f / (red[0] + red[1] + red[2] + red[3]);
  __syncthreads();
  const float sinv = sinv_sh;
  const float* xb = x + (size_t)b * Tdim * Edim;
  float a0 = 0.0f, a1 = 0.0f;
  const int m0 = tid, m1 = tid + 256;
  for (int j = i; j < Tdim; ++j) {
    const float wgt = kernel_g((float)(j - i), inv_h);
    const float* xr = xb + (size_t)j * Edim;
    a0 += wgt * xr[2 * m0];
    a1 += wgt * xr[2 * m1];
  }
  const float v0 = graw[m0], v1 = graw[m1];
  const float g0 = fmaxf(v0, 0.0f) + log1pf(__expf(-fabsf(v0)));
  const float g1 = fmaxf(v1, 0.0f) + log1pf(__expf(-fabsf(v1)));
  const size_t o = ((size_t)(b * Tdim + i)) * Edim;
  const float* xi = xb + (size_t)i * Edim;
  out[o + 2 * m0]     = xi[2 * m0];
  out[o + 2 * m0 + 1] = a0 * sinv * g0;
  out[o + 2 * m1]     = xi[2 * m1];
  out[o + 2 * m1 + 1] = a1 * sinv * g1;
}

extern "C" void kernel_launch(void* const* d_in, const int* in_sizes, int n_in,
                              void* d_out, int out_size, void* d_ws, size_t ws_size,
                              hipStream_t stream) {
  const float* x = (const float*)d_in[0];
  // d_in[1] is the triu mask: always upper-triangular by construction; folded analytically.
  const float* gate_raw = (const float*)d_in[2];
  float* out = (float*)d_out;

  const size_t XcT_bytes = (size_t)Bdim * Mdim * Tdim * 2;            // 16 MiB
  const size_t K_bytes   = (size_t)Tdim * Tdim * 2;                   // 32 MiB
  const size_t phi_bytes = (size_t)Bdim * Tdim * Mdim * sizeof(float);// 32 MiB
  const size_t need = XcT_bytes + K_bytes + phi_bytes +
                      (size_t)(Tdim + Mdim) * sizeof(float);

  if (ws_size < need) {
    fallback_kernel<<<dim3(Tdim, Bdim), 256, 0, stream>>>(x, gate_raw, out);
    return;
  }

  char* ws = (char*)d_ws;
  unsigned short* XcT  = (unsigned short*)ws;
  unsigned short* Kmat = (unsigned short*)(ws + XcT_bytes);
  float* phi           = (float*)(ws + XcT_bytes + K_bytes);
  float* inv_rowsum    = (float*)(ws + XcT_bytes + K_bytes + phi_bytes);
  float* gate          = inv_rowsum + Tdim;

  // phi must be zero every call (ws is re-poisoned 0xAA before each launch)
  hipMemsetAsync(phi, 0, phi_bytes, stream);
  gate_kernel<<<dim3((Mdim + 255) / 256), 256, 0, stream>>>(gate_raw, gate);
  rowsum_kernel<<<dim3(Tdim), 256, 0, stream>>>(inv_rowsum);
  kgen_kernel<<<dim3(Tdim / (256 * 8), Tdim), 256, 0, stream>>>(inv_rowsum, Kmat);
  extract_kernel<<<dim3(Tdim / 64, Mdim / 32, Bdim), 256, 0, stream>>>(x, XcT);
  gemm_kernel<<<dim3(80, Mdim / 128, Bdim), 256, 0, stream>>>(Kmat, XcT, phi);
  finalize_kernel<<<dim3((Bdim * Tdim * Edim) / 4 / 256), 256, 0, stream>>>(x, phi, gate, out);
}

// Round 3
// 247.795 us; speedup vs baseline: 1.1418x; 1.1418x over previous
//
#include <hip/hip_runtime.h>
#include <cstdint>
#include <cstddef>

// Problem constants (reference: B=4, T=4096, E=1024, M=E/2=512)
#define Tdim 4096
#define Bdim 4
#define Edim 1024
#define Mdim 512
#define EPSF 1e-6f

typedef __bf16 bf16x8 __attribute__((ext_vector_type(8)));
typedef float f32x4 __attribute__((ext_vector_type(4)));

// float -> bf16 bits, round-to-nearest-even
__device__ __forceinline__ unsigned short f2bf(float f) {
  union { float f; unsigned int u; } a; a.f = f;
  unsigned int r = a.u + 0x7fffu + ((a.u >> 16) & 1u);
  return (unsigned short)(r >> 16);
}

// bump kernel g(u) = exp(1 - 1/(1-u^2+eps)); reference's u>=1-EPS clamp can
// never fire for j<=T-1 (u_max = 1 - 1/horizon), so it is omitted.
__device__ __forceinline__ float kernel_g(float dj, float inv_h) {
  float u = fminf(dj * inv_h, 1.0f - EPSF);
  return __expf(1.0f - 1.0f / (1.0f - u * u + EPSF));
}

typedef void __attribute__((address_space(1)))* gas1;
typedef void __attribute__((address_space(3)))* las3;
// async global->LDS, 16B per lane; LDS dest = wave-uniform base + lane*16
__device__ __forceinline__ void load_lds16(const void* g, void* l) {
  __builtin_amdgcn_global_load_lds((gas1)(g), (las3)(l), 16, 0, 0);
}

// ---------------- prep kernels ----------------

__global__ __launch_bounds__(256) void gate_kernel(const float* __restrict__ graw,
                                                   float* __restrict__ gate) {
  const int m = blockIdx.x * 256 + threadIdx.x;
  if (m < Mdim) {
    const float v = graw[m];
    gate[m] = fmaxf(v, 0.0f) + log1pf(__expf(-fabsf(v)));  // stable softplus
  }
}

__global__ __launch_bounds__(256) void rowsum_kernel(float* __restrict__ inv_rowsum) {
  const int i = blockIdx.x;
  const int tid = threadIdx.x;
  const float inv_h = 1.0f / (float)(Tdim - i);
  float s = 0.0f;
  for (int j = i + tid; j < Tdim; j += 256)
    s += kernel_g((float)(j - i), inv_h);
#pragma unroll
  for (int off = 32; off; off >>= 1) s += __shfl_down(s, off);
  __shared__ float red[4];
  if ((tid & 63) == 0) red[tid >> 6] = s;
  __syncthreads();
  if (tid == 0) inv_rowsum[i] = 1.0f / (red[0] + red[1] + red[2] + red[3]);
}

// K matrix, normalized, bf16, zeros below diagonal. grid (2, T)
__global__ __launch_bounds__(256) void kgen_kernel(const float* __restrict__ inv_rowsum,
                                                   unsigned short* __restrict__ Kmat) {
  const int i = blockIdx.y;
  const int j0 = (blockIdx.x * 256 + threadIdx.x) * 8;
  union { unsigned short u[8]; uint4 v; } pk;
  if (j0 + 7 < i) {
    pk.v = make_uint4(0u, 0u, 0u, 0u);
  } else {
    const float inv_h = 1.0f / (float)(Tdim - i);
    const float inv_s = inv_rowsum[i];
#pragma unroll
    for (int t = 0; t < 8; ++t) {
      const int j = j0 + t;
      float r = 0.0f;
      if (j >= i) r = kernel_g((float)(j - i), inv_h) * inv_s;
      pk.u[t] = f2bf(r);
    }
  }
  *reinterpret_cast<uint4*>(&Kmat[(size_t)i * Tdim + j0]) = pk.v;
}

// XcT[b][m][j] = bf16(x[b][j][2m])  (transposed so GEMM B-frag is k-contiguous)
// tile: 64 j x 32 m per block. grid (T/64, M/32, B)
__global__ __launch_bounds__(256) void extract_kernel(const float* __restrict__ x,
                                                      unsigned short* __restrict__ XcT) {
  __shared__ unsigned short Ls[32][68];
  const int j0 = blockIdx.x * 64;
  const int m0 = blockIdx.y * 32;
  const int b  = blockIdx.z;
  const int tid = threadIdx.x;
  const int q = tid & 15;        // float4 chunk along e
  const int jbase = tid >> 4;    // 0..15
#pragma unroll
  for (int it = 0; it < 4; ++it) {
    const int jj = jbase + it * 16;
    const size_t off = ((size_t)(b * Tdim + j0 + jj)) * Edim + 2 * m0 + 4 * q;
    const float4 v = *reinterpret_cast<const float4*>(&x[off]);
    Ls[2 * q][jj]     = f2bf(v.x);   // even channel of m0+2q
    Ls[2 * q + 1][jj] = f2bf(v.z);   // even channel of m0+2q+1
  }
  __syncthreads();
  const int ch = tid & 15;
  const int mb = tid >> 4;
#pragma unroll
  for (int it = 0; it < 2; ++it) {
    const int m = mb + it * 16;
    ushort4 uv;
    uv.x = Ls[m][4 * ch];
    uv.y = Ls[m][4 * ch + 1];
    uv.z = Ls[m][4 * ch + 2];
    uv.w = Ls[m][4 * ch + 3];
    *reinterpret_cast<ushort4*>(
        &XcT[((size_t)(b * Mdim + m0 + m)) * Tdim + j0 + 4 * ch]) = uv;
  }
}

// ---------------- GEMM: phi[b,i,m] = K[i,:] @ Xc[b,:,m], fused output write --------
// C-tile 128(i) x 128(m), BK=64, 4 waves, 4x4 frags of 16x16x32 per wave.
// One block OWNS its C-tile (no atomics). Triangular imbalance handled by LPT
// dispatch: blockIdx.x = i-tile, heavy (p=0: 64 iters) dispatched first; grid
// 512 blocks over 256 CUs, per-CU quota 66 iters >= longest block 64, so
// greedy backfill balances. Single-barrier double-buffered K-loop: barrier at
// loop top (its vmcnt(0) drain makes current tile resident), THEN issue next
// tile's global_load_lds into the other buffer, then compute -> loads are in
// flight during compute instead of being drained immediately after issue.
// LDS XOR swizzle as before: 16B slot s of row r holds logical chunk s^(r&7).
__global__ __launch_bounds__(256) void gemm_kernel(
    const unsigned short* __restrict__ Kmat,
    const unsigned short* __restrict__ XcT,
    const float* __restrict__ x,
    const float* __restrict__ gate,
    float* __restrict__ out) {
  const int p  = blockIdx.x;        // i-tile; p=0 heaviest, dispatched first
  const int i0 = p * 128;
  const int m0 = blockIdx.y * 128;
  const int b  = blockIdx.z;

  __shared__ unsigned short As[2][128 * 64];  // K rows i0.., swizzled 16B slots
  __shared__ unsigned short Bs[2][128 * 64];  // XcT rows m0.., swizzled
  const int tid = threadIdx.x;
  const int w = tid >> 6;
  const int l = tid & 63;
  f32x4 acc[4][4] = {};
  const int wr = w >> 1, wc = w & 1;
  const unsigned short* Arow = Kmat + (size_t)i0 * Tdim;
  const unsigned short* Brow = XcT + ((size_t)b * Mdim + m0) * Tdim;
  const int srow  = l >> 3;                   // row within 8-row group
  const int sslot = l & 7;                    // linear 16B slot this lane fills
  const int schunk = (sslot ^ srow) * 8;      // swizzled source chunk (bf16 units)

  // preload first tile into buffer 0
#pragma unroll
  for (int t = 0; t < 4; ++t) {
    const int rr = (w * 4 + t) * 8 + srow;
    load_lds16(Arow + (size_t)rr * Tdim + (i0 + schunk), &As[0][(w * 4 + t) * 512]);
    load_lds16(Brow + (size_t)rr * Tdim + (i0 + schunk), &Bs[0][(w * 4 + t) * 512]);
  }

  int cur = 0;
  const int lr16 = l & 15;
  const int kq = l >> 4;  // 0..3: which 16B chunk quarter of the k-dim
  for (int j0 = i0; j0 < Tdim; j0 += 64, cur ^= 1) {
    __syncthreads();  // vmcnt(0) drain: tile `cur` resident; prev compute done
    const int jn = j0 + 64;
    if (jn < Tdim) {  // issue next tile's loads, then compute under them
#pragma unroll
      for (int t = 0; t < 4; ++t) {
        const int rr = (w * 4 + t) * 8 + srow;
        load_lds16(Arow + (size_t)rr * Tdim + (jn + schunk), &As[cur ^ 1][(w * 4 + t) * 512]);
        load_lds16(Brow + (size_t)rr * Tdim + (jn + schunk), &Bs[cur ^ 1][(w * 4 + t) * 512]);
      }
    }
#pragma unroll
    for (int kk = 0; kk < 2; ++kk) {
      bf16x8 af[4], bfr[4];
      const int chunk = kk * 4 + kq;
      const int slot = (chunk ^ (lr16 & 7)) * 8;   // un-swizzle
#pragma unroll
      for (int r = 0; r < 4; ++r)
        af[r] = *reinterpret_cast<const bf16x8*>(&As[cur][(wr * 64 + r * 16 + lr16) * 64 + slot]);
#pragma unroll
      for (int c = 0; c < 4; ++c)
        bfr[c] = *reinterpret_cast<const bf16x8*>(&Bs[cur][(wc * 64 + c * 16 + lr16) * 64 + slot]);
#pragma unroll
      for (int r = 0; r < 4; ++r)
#pragma unroll
        for (int c = 0; c < 4; ++c)
          acc[r][c] = __builtin_amdgcn_mfma_f32_16x16x32_bf16(af[r], bfr[c], acc[r][c], 0, 0, 0);
    }
  }

  // fused epilogue: C/D layout col=lane&15 (m), row=(lane>>4)*4+reg (i).
  // out even = x even (exact fp32 passthrough), odd = phi*gate. float2 stores
  // from 16 consecutive lanes = contiguous 128B segments.
  const int lr = l & 15;
  const int lq = l >> 4;
#pragma unroll
  for (int r = 0; r < 4; ++r) {
    const int i = i0 + wr * 64 + r * 16 + lq * 4;
#pragma unroll
    for (int c = 0; c < 4; ++c) {
      const int m = m0 + wc * 64 + c * 16 + lr;
      const float gm = gate[m];
#pragma unroll
      for (int v = 0; v < 4; ++v) {
        const size_t o = ((size_t)(b * Tdim + i + v)) * Edim + 2 * m;
        const float2 xv = *reinterpret_cast<const float2*>(&x[o]);
        float2 res;
        res.x = xv.x;
        res.y = acc[r][c][v] * gm;
        *reinterpret_cast<float2*>(&out[o]) = res;
      }
    }
  }
}

// ---------------- slow-but-correct fallback (only if ws too small) ----------------
__global__ __launch_bounds__(256) void fallback_kernel(const float* __restrict__ x,
                                                       const float* __restrict__ graw,
                                                       float* __restrict__ out) {
  const int i = blockIdx.x, b = blockIdx.y, tid = threadIdx.x;
  const float inv_h = 1.0f / (float)(Tdim - i);
  float s = 0.0f;
  for (int j = i + tid; j < Tdim; j += 256)
    s += kernel_g((float)(j - i), inv_h);
#pragma unroll
  for (int off = 32; off; off >>= 1) s += __shfl_down(s, off);
  __shared__ float red[4];
  __shared__ float sinv_sh;
  if ((tid & 63) == 0) red[tid >> 6] = s;
  __syncthreads();
  if (tid == 0) sinv_sh = 1.0f / (red[0] + red[1] + red[2] + red[3]);
  __syncthreads();
  const float sinv = sinv_sh;
  const float* xb = x + (size_t)b * Tdim * Edim;
  float a0 = 0.0f, a1 = 0.0f;
  const int m0 = tid, m1 = tid + 256;
  for (int j = i; j < Tdim; ++j) {
    const float wgt = kernel_g((float)(j - i), inv_h);
    const float* xr = xb + (size_t)j * Edim;
    a0 += wgt * xr[2 * m0];
    a1 += wgt * xr[2 * m1];
  }
  const float v0 = graw[m0], v1 = graw[m1];
  const float g0 = fmaxf(v0, 0.0f) + log1pf(__expf(-fabsf(v0)));
  const float g1 = fmaxf(v1, 0.0f) + log1pf(__expf(-fabsf(v1)));
  const size_t o = ((size_t)(b * Tdim + i)) * Edim;
  const float* xi = xb + (size_t)i * Edim;
  out[o + 2 * m0]     = xi[2 * m0];
  out[o + 2 * m0 + 1] = a0 * sinv * g0;
  out[o + 2 * m1]     = xi[2 * m1];
  out[o + 2 * m1 + 1] = a1 * sinv * g1;
}

extern "C" void kernel_launch(void* const* d_in, const int* in_sizes, int n_in,
                              void* d_out, int out_size, void* d_ws, size_t ws_size,
                              hipStream_t stream) {
  const float* x = (const float*)d_in[0];
  // d_in[1] is the triu mask: always upper-triangular by construction; folded analytically.
  const float* gate_raw = (const float*)d_in[2];
  float* out = (float*)d_out;

  const size_t XcT_bytes = (size_t)Bdim * Mdim * Tdim * 2;  // 16 MiB
  const size_t K_bytes   = (size_t)Tdim * Tdim * 2;         // 32 MiB
  const size_t need = XcT_bytes + K_bytes + (size_t)(Tdim + Mdim) * sizeof(float);

  if (ws_size < need) {
    fallback_kernel<<<dim3(Tdim, Bdim), 256, 0, stream>>>(x, gate_raw, out);
    return;
  }

  char* ws = (char*)d_ws;
  unsigned short* XcT  = (unsigned short*)ws;
  unsigned short* Kmat = (unsigned short*)(ws + XcT_bytes);
  float* inv_rowsum    = (float*)(ws + XcT_bytes + K_bytes);
  float* gate          = inv_rowsum + Tdim;

  gate_kernel<<<dim3((Mdim + 255) / 256), 256, 0, stream>>>(gate_raw, gate);
  rowsum_kernel<<<dim3(Tdim), 256, 0, stream>>>(inv_rowsum);
  kgen_kernel<<<dim3(Tdim / (256 * 8), Tdim), 256, 0, stream>>>(inv_rowsum, Kmat);
  extract_kernel<<<dim3(Tdim / 64, Mdim / 32, Bdim), 256, 0, stream>>>(x, XcT);
  // LPT: blockIdx.x (i-tile) fastest-varying -> heavy tiles dispatched first
  gemm_kernel<<<dim3(Tdim / 128, Mdim / 128, Bdim), 256, 0, stream>>>(Kmat, XcT, x, gate, out);
}